// Round 1
// baseline (16423.108 us; speedup 1.0000x reference)
//
#include <hip/hip_runtime.h>
#include <cmath>

// Problem dims (fixed by reference)
#define SEQ 512
#define BATCH 2048
#define DIM 64
#define HID 128

#define BT 4          // batch elements per block
#define THREADS 128   // one thread per hidden index j

// 512 blocks x 128 threads; 2 waves/block, 4 blocks/CU -> 8 waves/CU (2/SIMD).
// Weights live in VGPRs (per-lane j rows); activations are wave-uniform and
// come from L1 (x) or LDS broadcast (wih_x).
__global__ __launch_bounds__(THREADS, 2)
void rnn_kernel(const float* __restrict__ x,
                const float* __restrict__ h0,
                const float* __restrict__ W_ih,
                const float* __restrict__ b_ih,
                const float* __restrict__ W_hh,
                const float* __restrict__ b_hh,
                float* __restrict__ out) {
    // double-buffered wih_x tile: one barrier per step is then sufficient
    __shared__ float wihx_lds[2][BT][HID];

    const int j = threadIdx.x;              // hidden index 0..127
    const int bbase = blockIdx.x * BT;      // first batch element of this block

    // ---- load weight rows into registers (once) ----
    float4 wih[DIM / 4];
    {
        const float4* p = reinterpret_cast<const float4*>(W_ih + j * DIM);
#pragma unroll
        for (int k = 0; k < DIM / 4; ++k) wih[k] = p[k];
    }
    float4 whh[HID / 4];
    {
        const float4* p = reinterpret_cast<const float4*>(W_hh + j * HID);
#pragma unroll
        for (int k = 0; k < HID / 4; ++k) whh[k] = p[k];
    }
    const float bi = b_ih[j];
    const float bh = b_hh[j];

    float h[BT];
#pragma unroll
    for (int b = 0; b < BT; ++b) h[b] = h0[(bbase + b) * HID + j];

    for (int t = 0; t < SEQ; ++t) {
        const int buf = t & 1;

        // ---- GEMM1: a1[b] = sum_k W_ih[j][k] * x[t][bbase+b][k] ----
        float a1[BT];
#pragma unroll
        for (int b = 0; b < BT; ++b) a1[b] = 0.0f;

        const float4* xrow = reinterpret_cast<const float4*>(
            x + (size_t)t * BATCH * DIM + (size_t)bbase * DIM);
#pragma unroll
        for (int k4 = 0; k4 < DIM / 4; ++k4) {
            const float4 w = wih[k4];
#pragma unroll
            for (int b = 0; b < BT; ++b) {
                const float4 xv = xrow[b * (DIM / 4) + k4];  // lane-uniform addr
                a1[b] += w.x * xv.x + w.y * xv.y + w.z * xv.z + w.w * xv.w;
            }
        }

        // ---- scale by h, share via LDS ----
        float wihx[BT];
#pragma unroll
        for (int b = 0; b < BT; ++b) {
            wihx[b] = (a1[b] + bi) * h[b];
            wihx_lds[buf][b][j] = wihx[b];   // contiguous across lanes
        }
        __syncthreads();

        // ---- GEMM2: a2[b] = sum_k W_hh[j][k] * wihx[b][k] ----
        float a2[BT];
#pragma unroll
        for (int b = 0; b < BT; ++b) a2[b] = 0.0f;
#pragma unroll
        for (int k4 = 0; k4 < HID / 4; ++k4) {
            const float4 w = whh[k4];
#pragma unroll
            for (int b = 0; b < BT; ++b) {
                const float4 v = *reinterpret_cast<const float4*>(
                    &wihx_lds[buf][b][k4 * 4]);  // lane-uniform -> broadcast
                a2[b] += w.x * v.x + w.y * v.y + w.z * v.z + w.w * v.w;
            }
        }

        // ---- h update ----
#pragma unroll
        for (int b = 0; b < BT; ++b) {
            const float whhv = (a2[b] + bh) * h[b];
            h[b] = tanhf(wihx[b] + whhv);
        }
        // no second barrier: double buffer + the step-t+1 barrier covers WAR
    }

#pragma unroll
    for (int b = 0; b < BT; ++b) out[(bbase + b) * HID + j] = h[b];
}

extern "C" void kernel_launch(void* const* d_in, const int* in_sizes, int n_in,
                              void* d_out, int out_size, void* d_ws, size_t ws_size,
                              hipStream_t stream) {
    const float* x    = (const float*)d_in[0];
    const float* h0   = (const float*)d_in[1];
    const float* W_ih = (const float*)d_in[2];
    const float* b_ih = (const float*)d_in[3];
    const float* W_hh = (const float*)d_in[4];
    const float* b_hh = (const float*)d_in[5];
    float* out = (float*)d_out;

    dim3 grid(BATCH / BT);   // 512 blocks
    dim3 block(THREADS);     // 128 threads
    rnn_kernel<<<grid, block, 0, stream>>>(x, h0, W_ih, b_ih, W_hh, b_hh, out);
}

// Round 3
// 5532.475 us; speedup vs baseline: 2.9685x; 2.9685x over previous
//
#include <hip/hip_runtime.h>
#include <cmath>

// Problem dims (fixed by reference)
#define SEQ 512
#define BATCH 2048
#define DIM 64
#define HID 128

// Design: 64-thread (single-wave) blocks. Lane owns hidden rows j0=lane,
// j1=lane+64 and BT=2 batch elements -> 1024 blocks covers 2048x128 outputs
// at 4 waves/CU (1/SIMD). Weights live in ~384 named-VGPR float4 scalars
// (arrays spilled to scratch in round 1 -> 43 GB of traffic). Activations
// are shared via tiny LDS tiles read at wave-uniform (broadcast) addresses.

#define R16(M) M(0) M(1) M(2) M(3) M(4) M(5) M(6) M(7) M(8) M(9) M(10) M(11) M(12) M(13) M(14) M(15)
#define R32(M) R16(M) M(16) M(17) M(18) M(19) M(20) M(21) M(22) M(23) M(24) M(25) M(26) M(27) M(28) M(29) M(30) M(31)

// NOTE: macro params must not be named 'w'/'x'/'y'/'z' — substitution would
// also rewrite the .w/.x/.y/.z member tokens (round-2 compile failure).
#define DOT4(acc, W_, V_) acc += W_.x*V_.x; acc += W_.y*V_.y; acc += W_.z*V_.z; acc += W_.w*V_.w;

__global__ __launch_bounds__(64, 1)
void rnn_kernel(const float* __restrict__ x,
                const float* __restrict__ h0,
                const float* __restrict__ W_ih,
                const float* __restrict__ b_ih,
                const float* __restrict__ W_hh,
                const float* __restrict__ b_hh,
                float* __restrict__ out) {
    // LDS tiles, read at wave-uniform addresses (broadcast, conflict-free)
    __shared__ float4 xs4[2][DIM / 4];    // x tile      [batch][k4]
    __shared__ float4 act4[2][HID / 4];   // wih_x tile  [batch][k4]
    float* actf = (float*)act4;

    const int lane = threadIdx.x;         // 0..63
    const int j0 = lane;
    const int j1 = lane + 64;
    const int b0 = blockIdx.x * 2;

    // ---- weights into named registers (cannot be demoted to scratch) ----
    const float4* wiAp = (const float4*)(W_ih + j0 * DIM);
    const float4* wiBp = (const float4*)(W_ih + j1 * DIM);
    const float4* whAp = (const float4*)(W_hh + j0 * HID);
    const float4* whBp = (const float4*)(W_hh + j1 * HID);
#define DECL_WI(i) float4 wiA##i = wiAp[i]; float4 wiB##i = wiBp[i];
    R16(DECL_WI)
#define DECL_WH(i) float4 whA##i = whAp[i]; float4 whB##i = whBp[i];
    R32(DECL_WH)

    const float biA = b_ih[j0], biB = b_ih[j1];
    const float bhA = b_hh[j0], bhB = b_hh[j1];

    float hA0 = h0[(b0 + 0) * HID + j0];
    float hA1 = h0[(b0 + 1) * HID + j0];
    float hB0 = h0[(b0 + 0) * HID + j1];
    float hB1 = h0[(b0 + 1) * HID + j1];

    // per-lane x staging slot: lane -> (batch = lane/32, k = (lane%32)*2)
    const int xb = lane >> 5;
    const int xk = (lane & 31) * 2;
    const float* xbase = x + (size_t)(b0 + xb) * DIM + xk;
    float2* xsf2 = (float2*)xs4;          // float2 index = xb*32 + (lane&31)
    const int xslot = xb * 32 + (lane & 31);

    // prologue: stage x(0)
    float2 xcur = *(const float2*)(xbase);
    xsf2[xslot] = xcur;
    __syncthreads();

    for (int t = 0; t < SEQ; ++t) {
        // prefetch x(t+1) into registers (window ~ full iteration)
        const int tn = (t < SEQ - 1) ? t + 1 : t;
        const float2 xnext = *(const float2*)(xbase + (size_t)tn * BATCH * DIM);

        // ---- GEMM1: a = W_ih[j,:] . x[t,b,:]  (x broadcast from LDS) ----
        float aA0 = 0.f, aA1 = 0.f, aB0 = 0.f, aB1 = 0.f;
#define G1(i) { const float4 xv0 = xs4[0][i]; const float4 xv1 = xs4[1][i]; \
                DOT4(aA0, wiA##i, xv0) DOT4(aA1, wiA##i, xv1) \
                DOT4(aB0, wiB##i, xv0) DOT4(aB1, wiB##i, xv1) }
        R16(G1)

        const float wA0 = (aA0 + biA) * hA0;
        const float wA1 = (aA1 + biA) * hA1;
        const float wB0 = (aB0 + biB) * hB0;
        const float wB1 = (aB1 + biB) * hB1;

        // share wih_x across lanes
        actf[0 * HID + j0] = wA0;
        actf[0 * HID + j1] = wB0;
        actf[1 * HID + j0] = wA1;
        actf[1 * HID + j1] = wB1;
        __syncthreads();   // single wave: compiles to cheap barrier + waitcnt

        // ---- GEMM2: c = W_hh[j,:] . wih_x[b,:]  (broadcast from LDS) ----
        float cA0 = 0.f, cA1 = 0.f, cB0 = 0.f, cB1 = 0.f;
#define G2(i) { const float4 v0 = act4[0][i]; const float4 v1 = act4[1][i]; \
                DOT4(cA0, whA##i, v0) DOT4(cA1, whA##i, v1) \
                DOT4(cB0, whB##i, v0) DOT4(cB1, whB##i, v1) }
        R32(G2)

        // stage x(t+1) (GEMM1 reads of this iter are done; wave-ordered)
        xsf2[xslot] = xnext;

        // ---- h update ----
        hA0 = tanhf(wA0 + (cA0 + bhA) * hA0);
        hA1 = tanhf(wA1 + (cA1 + bhA) * hA1);
        hB0 = tanhf(wB0 + (cB0 + bhB) * hB0);
        hB1 = tanhf(wB1 + (cB1 + bhB) * hB1);
        __syncthreads();
    }

    out[(b0 + 0) * HID + j0] = hA0;
    out[(b0 + 0) * HID + j1] = hB0;
    out[(b0 + 1) * HID + j0] = hA1;
    out[(b0 + 1) * HID + j1] = hB1;
}

extern "C" void kernel_launch(void* const* d_in, const int* in_sizes, int n_in,
                              void* d_out, int out_size, void* d_ws, size_t ws_size,
                              hipStream_t stream) {
    const float* x    = (const float*)d_in[0];
    const float* h0   = (const float*)d_in[1];
    const float* W_ih = (const float*)d_in[2];
    const float* b_ih = (const float*)d_in[3];
    const float* W_hh = (const float*)d_in[4];
    const float* b_hh = (const float*)d_in[5];
    float* out = (float*)d_out;

    dim3 grid(BATCH / 2);   // 1024 blocks, 2 batch elements each
    dim3 block(64);         // single wave per block
    rnn_kernel<<<grid, block, 0, stream>>>(x, h0, W_ih, b_ih, W_hh, b_hh, out);
}